// Round 10
// baseline (1048.884 us; speedup 1.0000x reference)
//
#include <hip/hip_runtime.h>
#include <hip/hip_fp16.h>
#include <math.h>

namespace {

constexpr int kN1 = 20001;        // NUM_NODES + 1 (output rows)
constexpr int kNE = 1000000;      // NUM_EDGES
constexpr int kNStep = 6;
constexpr int kHid = 128;
constexpr int kB = 64;            // B_SET
constexpr int kNRel2 = 24;        // 2*NUM_REL
constexpr float kEps = 1e-10f;
constexpr int kNXcd = 8;
constexpr int kScanBlocks = (kN1 + 255) / 256;  // 79
constexpr int kStride = 20032;    // column stride (16B-aligned, > kN1)
constexpr int kChunk = 2501;      // dst-nodes per chunk; 8 chunks cover 20008
constexpr int kNChunk = 8;

typedef float f32x4 __attribute__((ext_vector_type(4)));

__device__ __forceinline__ float sig(float x) { return 1.0f / (1.0f + expf(-x)); }

// ---------------- LSTM front-end ----------------

__global__ __launch_bounds__(256) void transpose_w_kernel(
    const float* __restrict__ w_ih, const float* __restrict__ w_hh,
    float* __restrict__ wt) {
  const int idx = blockIdx.x * 256 + threadIdx.x;
  if (idx < 256 * 512) {
    const int k = idx >> 9;
    const int j = idx & 511;
    wt[idx] = (k < 128) ? w_ih[j * kHid + k] : w_hh[j * kHid + (k - 128)];
  }
}

__global__ __launch_bounds__(512) void lstm_fast_kernel(
    const float* __restrict__ query_emb, const float* __restrict__ wt,
    const float* __restrict__ b_ih, const float* __restrict__ b_hh,
    const int* __restrict__ r_set, float* __restrict__ hidden /* (6,64,128) */) {
  const int b = blockIdx.x;
  const int tid = threadIdx.x;
  __shared__ float xh[256];     // [0..127]=x, [128..255]=h
  __shared__ float cst[kHid];
  __shared__ float gsm[512];
  const float bias = b_ih[tid] + b_hh[tid];
  const int q = r_set[b];
  if (tid < kHid) { cst[tid] = 0.f; xh[kHid + tid] = 0.f; }
  for (int s = 0; s < kNStep; ++s) {
    if (tid < kHid) xh[tid] = query_emb[((s < kNStep - 1) ? q : 12) * kHid + tid];
    __syncthreads();
    float acc = bias;
#pragma unroll 8
    for (int k = 0; k < 256; ++k) acc += xh[k] * wt[k * 512 + tid];
    gsm[tid] = acc;
    __syncthreads();
    if (tid < kHid) {
      const float ig = sig(gsm[tid]);
      const float fg = sig(gsm[kHid + tid]);
      const float gg = tanhf(gsm[2 * kHid + tid]);
      const float og = sig(gsm[3 * kHid + tid]);
      const float cn = fg * cst[tid] + ig * gg;
      cst[tid] = cn;
      const float hn = og * tanhf(cn);
      xh[kHid + tid] = hn;
      hidden[(s * kB + b) * kHid + tid] = hn;
    }
    __syncthreads();
  }
}

// Legacy LSTM (fallback path only).
__global__ __launch_bounds__(256) void lstm_kernel(
    const float* __restrict__ query_emb, const float* __restrict__ w_ih,
    const float* __restrict__ w_hh, const float* __restrict__ b_ih,
    const float* __restrict__ b_hh, const int* __restrict__ r_set,
    float* __restrict__ hidden) {
  const int b = blockIdx.x;
  const int tid = threadIdx.x;
  __shared__ float xs[kHid], hs[kHid], cs[kHid], gates[4 * kHid];
  if (tid < kHid) { hs[tid] = 0.f; cs[tid] = 0.f; }
  __syncthreads();
  for (int s = 0; s < kNStep; ++s) {
    const int q = (s < kNStep - 1) ? r_set[b] : 12;
    if (tid < kHid) xs[tid] = query_emb[q * kHid + tid];
    __syncthreads();
    for (int j = tid; j < 4 * kHid; j += blockDim.x) {
      const float* wi = &w_ih[j * kHid];
      const float* wh = &w_hh[j * kHid];
      float a = b_ih[j] + b_hh[j];
#pragma unroll 4
      for (int k = 0; k < kHid; ++k) a += xs[k] * wi[k] + hs[k] * wh[k];
      gates[j] = a;
    }
    __syncthreads();
    if (tid < kHid) {
      const float ig = sig(gates[tid]);
      const float fg = sig(gates[kHid + tid]);
      const float gg = tanhf(gates[2 * kHid + tid]);
      const float og = sig(gates[3 * kHid + tid]);
      const float cn = fg * cs[tid] + ig * gg;
      const float hn = og * tanhf(cn);
      cs[tid] = cn;
      hs[tid] = hn;
      hidden[(s * kB + b) * kHid + tid] = hn;
    }
    __syncthreads();
  }
}

__global__ __launch_bounds__(128) void attn_weight_kernel(
    const float* __restrict__ hidden, const float* __restrict__ wl_w,
    const float* __restrict__ wl_b, float* __restrict__ attnAll /* (6,6,64) */,
    float* __restrict__ weightAll /* (6,24,64) */) {
  const int b = blockIdx.x;
  const int tid = threadIdx.x;
  __shared__ float hsm[kNStep][kHid];
  __shared__ float G[kNStep][kNStep];
  __shared__ float logits[kNStep][kNRel2];
  for (int s = 0; s < kNStep; ++s) hsm[s][tid] = hidden[(s * kB + b) * kHid + tid];
  __syncthreads();
  if (tid < 36) {
    const int i = tid / 6, t = tid % 6;
    if (t <= i) {
      float acc = 0.f;
      for (int k = 0; k < kHid; ++k) acc += hsm[i][k] * hsm[t][k];
      G[i][t] = acc;
    }
  }
  for (int p = tid; p < kNStep * kNRel2; p += 128) {
    const int i = p / kNRel2, r = p % kNRel2;
    float acc = wl_b[r];
    for (int k = 0; k < kHid; ++k) acc += hsm[i][k] * wl_w[r * kHid + k];
    logits[i][r] = acc;
  }
  __syncthreads();
  if (tid < kNStep) {
    const int i = tid;
    float m = G[i][0];
    for (int t = 1; t <= i; ++t) m = fmaxf(m, G[i][t]);
    float ssum = 0.f;
    float ev[kNStep];
    for (int t = 0; t <= i; ++t) { ev[t] = expf(G[i][t] - m); ssum += ev[t]; }
    for (int t = 0; t <= i; ++t) attnAll[(i * kNStep + t) * kB + b] = ev[t] / ssum;
    float mw = logits[i][0];
    for (int r = 1; r < kNRel2; ++r) mw = fmaxf(mw, logits[i][r]);
    float sw = 0.f;
    float ew[kNRel2];
    for (int r = 0; r < kNRel2; ++r) { ew[r] = expf(logits[i][r] - mw); sw += ew[r]; }
    for (int r = 0; r < kNRel2; ++r) weightAll[(i * kNRel2 + r) * kB + b] = ew[r] / sw;
  }
}

// ---------------- edge preprocessing (once per launch) ----------------

__global__ __launch_bounds__(256) void zero_kernel(int* __restrict__ count2,
                                                   float* __restrict__ colsumAll) {
  const int i = blockIdx.x * blockDim.x + threadIdx.x;
  if (i < kN1 * kNXcd) count2[i] = 0;
  if (i < kNStep * kB) colsumAll[i] = 0.f;
}

// Per-(node, xcd) histogram. MUST use the same grid/stride as permute_kernel.
__global__ __launch_bounds__(256) void hist2_kernel(const int* __restrict__ nout,
                                                    int* __restrict__ count2) {
  const int xcd = blockIdx.x & (kNXcd - 1);
  for (int e = blockIdx.x * blockDim.x + threadIdx.x; e < kNE;
       e += gridDim.x * blockDim.x)
    atomicAdd(&count2[nout[e] * kNXcd + xcd], 1);
}

// Scan phase A: per-node totals + per-block sums (unpadded).
__global__ __launch_bounds__(256) void scanA_kernel(const int* __restrict__ count2,
                                                    int* __restrict__ counts,
                                                    int* __restrict__ blockSum) {
  const int tid = threadIdx.x;
  const int n = blockIdx.x * 256 + tid;
  int c = 0;
  if (n < kN1) {
#pragma unroll
    for (int x = 0; x < kNXcd; ++x) c += count2[n * kNXcd + x];
    counts[n] = c;
  }
  __shared__ int sm[256];
  sm[tid] = c;
  __syncthreads();
  for (int off = 128; off > 0; off >>= 1) {
    if (tid < off) sm[tid] += sm[tid + off];
    __syncthreads();
  }
  if (tid == 0) blockSum[blockIdx.x] = sm[0];
}

__global__ __launch_bounds__(128) void scanB_kernel(int* __restrict__ blockSum) {
  const int tid = threadIdx.x;
  __shared__ int sm[128];
  const int v = (tid < kScanBlocks) ? blockSum[tid] : 0;
  sm[tid] = v;
  __syncthreads();
  for (int off = 1; off < 128; off <<= 1) {
    const int t = (tid >= off) ? sm[tid - off] : 0;
    __syncthreads();
    sm[tid] += t;
    __syncthreads();
  }
  if (tid < kScanBlocks) blockSum[tid] = sm[tid] - v;  // exclusive
}

// Scan phase C: block-local scan; write offsets + per-(node,xcd) cursors.
__global__ __launch_bounds__(256) void scanC_kernel(const int* __restrict__ counts,
                                                    const int* __restrict__ blockSum,
                                                    int* __restrict__ count2,
                                                    int* __restrict__ offsets) {
  const int tid = threadIdx.x;
  const int n = blockIdx.x * 256 + tid;
  const int c = (n < kN1) ? counts[n] : 0;
  __shared__ int sm[256];
  sm[tid] = c;
  __syncthreads();
  for (int off = 1; off < 256; off <<= 1) {
    const int t = (tid >= off) ? sm[tid - off] : 0;
    __syncthreads();
    sm[tid] += t;
    __syncthreads();
  }
  const int excl = sm[tid] - c + blockSum[blockIdx.x];
  if (n < kN1) {
    offsets[n] = excl;
    int sub = excl;
#pragma unroll
    for (int x = 0; x < kNXcd; ++x) {
      const int cc = count2[n * kNXcd + x];
      count2[n * kNXcd + x] = sub;  // becomes the cursor
      sub += cc;
    }
    if (n == kN1 - 1) offsets[kN1] = excl + c;
  }
}

// packed word: src (15b) | type (5b) | dstRel (12b). dstRel = dst - chunk*2501.
__global__ __launch_bounds__(256) void permute_kernel(
    const int* __restrict__ nin, const int* __restrict__ nout,
    const int* __restrict__ etype, int* __restrict__ cursor2,
    unsigned* __restrict__ packed) {
  const int xcd = blockIdx.x & (kNXcd - 1);
  for (int e = blockIdx.x * blockDim.x + threadIdx.x; e < kNE;
       e += gridDim.x * blockDim.x) {
    const int d = nout[e];
    const int pos = atomicAdd(&cursor2[d * kNXcd + xcd], 1);
    const int dr = d - (d / kChunk) * kChunk;
    packed[pos] =
        (unsigned)nin[e] | ((unsigned)etype[e] << 15) | ((unsigned)dr << 20);
  }
}

// ---------------- per-step kernels (column-major layout) ----------------

// inpT[b][n] (fp16, stride kStride). Grid: 64 cols x 10 n-blocks.
// Entries n in [kN1, kStride) are explicitly zero (LDS colv safety).
__global__ __launch_bounds__(256) void inpT_kernel(
    const float* __restrict__ attnAll, const float* __restrict__ colsumAll,
    const int* __restrict__ h_set, const float* __restrict__ outsT,
    __half* __restrict__ inpT, int step) {
  const int b = blockIdx.x / 10;
  const int n8 = (blockIdx.x % 10) * 256 + threadIdx.x;
  __shared__ float cf[kNStep];
  __shared__ int hb;
  if (threadIdx.x < kNStep) {
    float c = 0.f;
    if (threadIdx.x == 0)
      c = attnAll[(step * kNStep) * kB + b];
    else if (threadIdx.x <= step)
      c = attnAll[(step * kNStep + threadIdx.x) * kB + b] /
          fmaxf(colsumAll[(threadIdx.x - 1) * kB + b], kEps);
    cf[threadIdx.x] = c;
  }
  if (threadIdx.x == kNStep) hb = h_set[b];
  __syncthreads();
  if (n8 >= kStride / 8) return;
  const int n0 = n8 * 8;
  float v[8] = {0.f, 0.f, 0.f, 0.f, 0.f, 0.f, 0.f, 0.f};
  for (int t = 1; t <= step; ++t) {
    const float ct = cf[t];
    const float* src = outsT + ((long long)(t - 1) * kB + b) * kStride + n0;
    const f32x4 o0 = __builtin_nontemporal_load(reinterpret_cast<const f32x4*>(src));
    const f32x4 o1 =
        __builtin_nontemporal_load(reinterpret_cast<const f32x4*>(src + 4));
    v[0] += ct * o0.x; v[1] += ct * o0.y; v[2] += ct * o0.z; v[3] += ct * o0.w;
    v[4] += ct * o1.x; v[5] += ct * o1.y; v[6] += ct * o1.z; v[7] += ct * o1.w;
  }
  if (hb >= n0 && hb < n0 + 8) v[hb - n0] += cf[0];
#pragma unroll
  for (int j = 0; j < 8; ++j)
    if (n0 + j >= kN1) v[j] = 0.f;
  __half2 h0 = __floats2half2_rn(v[0], v[1]);
  __half2 h1 = __floats2half2_rn(v[2], v[3]);
  __half2 h2 = __floats2half2_rn(v[4], v[5]);
  __half2 h3 = __floats2half2_rn(v[6], v[7]);
  uint4 u;
  u.x = *reinterpret_cast<unsigned*>(&h0);
  u.y = *reinterpret_cast<unsigned*>(&h1);
  u.z = *reinterpret_cast<unsigned*>(&h2);
  u.w = *reinterpret_cast<unsigned*>(&h3);
  *reinterpret_cast<uint4*>(inpT + (long long)b * kStride + n0) = u;
}

// Core scatter, LDS mechanism: block = (column b, dst-chunk c). Column staged
// in LDS (40KB); packed streamed coalesced; random access is LDS-only (no
// vmem miss-queue limit). Same-dst runs pre-reduced in-register (8 edges per
// thread, consecutive) before LDS atomics. Output + colsum written coalesced.
__global__ __launch_bounds__(256) void gather_cols_kernel(
    const __half* __restrict__ inpT /* [64][kStride] */,
    const float* __restrict__ weight /* (24,64) step slice */,
    const unsigned* __restrict__ packed, const int* __restrict__ offsets,
    float* __restrict__ outT /* [64][kStride] step slice */,
    float* __restrict__ colsum /* [64] step slice */) {
  __shared__ __align__(16) __half colv[kStride];      // 40064 B
  __shared__ float outcol[kChunk];                    // 10004 B
  __shared__ float wcol32[kNRel2 * 32];               // 3072 B (2 lanes/bank)
  const int tid = threadIdx.x;
  const int b = blockIdx.x >> 3;
  const int c = blockIdx.x & 7;
  const int l32 = tid & 31;
  const int nLo = c * kChunk;
  const int nHi = min(nLo + kChunk, kN1);
  const int nN = nHi - nLo;
  {
    const uint4* src = reinterpret_cast<const uint4*>(inpT + (long long)b * kStride);
    uint4* dst = reinterpret_cast<uint4*>(colv);
    for (int i = tid; i < kStride / 8; i += 256) dst[i] = src[i];
  }
  for (int i = tid; i < kChunk; i += 256) outcol[i] = 0.f;
  for (int i = tid; i < kNRel2 * 32; i += 256)
    wcol32[i] = weight[(i >> 5) * kB + b];
  __syncthreads();
  const int eBeg = offsets[nLo];
  const int eEnd = offsets[nHi];
  for (int base = eBeg + tid * 8; base < eEnd; base += 2048) {
    const int cnt = min(8, eEnd - base);
    int curDr = -1;
    float accv = 0.f;
#pragma unroll
    for (int k = 0; k < 8; ++k) {
      if (k < cnt) {
        const unsigned u = packed[base + k];
        const float vw = __half2float(colv[u & 0x7fffu]) *
                         wcol32[((u >> 15) & 31u) * 32 + l32];
        const int dr = (int)(u >> 20);
        if (dr != curDr) {
          if (curDr >= 0) atomicAdd(&outcol[curDr], accv);
          curDr = dr;
          accv = 0.f;
        }
        accv += vw;
      }
    }
    if (curDr >= 0) atomicAdd(&outcol[curDr], accv);
  }
  __syncthreads();
  float s = 0.f;
  float* dstp = outT + (long long)b * kStride + nLo;
  for (int i = tid; i < nN; i += 256) {
    const float v = outcol[i];
    dstp[i] = v;
    s += v;
  }
#pragma unroll
  for (int off = 1; off < 64; off <<= 1) s += __shfl_xor(s, off);
  if ((tid & 63) == 0) unsafeAtomicAdd(&colsum[b], s);
}

__global__ __launch_bounds__(256) void scoreT_kernel(
    const float* __restrict__ outLastT, const float* __restrict__ colsumLast,
    const int* __restrict__ t_index, const int* __restrict__ hr_inverse,
    const float* __restrict__ lin_w, const float* __restrict__ lin_b,
    float* __restrict__ out, int n) {
  const int i = blockIdx.x * blockDim.x + threadIdx.x;
  if (i < n) {
    const int node = t_index[i];
    const int b = hr_inverse[i];
    const float v =
        outLastT[(long long)b * kStride + node] / fmaxf(colsumLast[b], kEps);
    out[i] = v * lin_w[0] + lin_b[0];
  }
}

// ---------------- fallback (row-major float-atomic scatter) ----------------

__global__ __launch_bounds__(256) void inp_zero_kernel(
    const float* __restrict__ attnAll, const int* __restrict__ h_set,
    const float* __restrict__ outs, float* __restrict__ inp,
    float* __restrict__ out_next, float* __restrict__ colsum, int step) {
  const long long total = (long long)kN1 * kB;
  for (long long idx = (long long)blockIdx.x * blockDim.x + threadIdx.x; idx < total;
       idx += (long long)gridDim.x * blockDim.x) {
    const int b = (int)(idx & 63);
    const int n = (int)(idx >> 6);
    float acc = (h_set[b] == n) ? attnAll[(step * kNStep) * kB + b] : 0.f;
    for (int t = 1; t <= step; ++t)
      acc += attnAll[(step * kNStep + t) * kB + b] *
             outs[(long long)(t - 1) * kN1 * kB + idx];
    inp[idx] = acc;
    out_next[idx] = 0.f;
  }
  if (blockIdx.x == 0 && threadIdx.x < kB) colsum[threadIdx.x] = 0.f;
}

__global__ __launch_bounds__(256) void scatter_kernel(
    const float* __restrict__ inp, const float* __restrict__ weight,
    const int* __restrict__ nin, const int* __restrict__ nout,
    const int* __restrict__ etype, float* __restrict__ out,
    float* __restrict__ colsum) {
  const int lane = threadIdx.x & 63;
  const int wave = blockIdx.x * (blockDim.x >> 6) + (threadIdx.x >> 6);
  const int nwave = gridDim.x * (blockDim.x >> 6);
  __shared__ float wsm[kNRel2 * kB];
  for (int j = threadIdx.x; j < kNRel2 * kB; j += blockDim.x) wsm[j] = weight[j];
  __syncthreads();
  float csum = 0.f;
  for (int e = wave; e < kNE; e += nwave) {
    const float v = inp[(long long)nin[e] * kB + lane] * wsm[etype[e] * kB + lane];
    unsafeAtomicAdd(&out[(long long)nout[e] * kB + lane], v);
    csum += v;
  }
  unsafeAtomicAdd(&colsum[lane], csum);
}

__global__ __launch_bounds__(256) void normalize_kernel(
    float* __restrict__ out, const float* __restrict__ colsum) {
  const long long total = (long long)kN1 * kB;
  for (long long idx = (long long)blockIdx.x * blockDim.x + threadIdx.x; idx < total;
       idx += (long long)gridDim.x * blockDim.x)
    out[idx] /= fmaxf(colsum[idx & 63], kEps);
}

__global__ __launch_bounds__(256) void score_kernel_norm(
    const float* __restrict__ outLast, const int* __restrict__ t_index,
    const int* __restrict__ hr_inverse, const float* __restrict__ lin_w,
    const float* __restrict__ lin_b, float* __restrict__ out, int n) {
  const int i = blockIdx.x * blockDim.x + threadIdx.x;
  if (i < n) {
    out[i] = outLast[(long long)t_index[i] * kB + hr_inverse[i]] * lin_w[0] + lin_b[0];
  }
}

}  // namespace

extern "C" void kernel_launch(void* const* d_in, const int* in_sizes, int n_in,
                              void* d_out, int out_size, void* d_ws, size_t ws_size,
                              hipStream_t stream) {
  const float* query_emb = (const float*)d_in[0];
  const float* w_ih = (const float*)d_in[1];
  const float* w_hh = (const float*)d_in[2];
  const float* b_ih = (const float*)d_in[3];
  const float* b_hh = (const float*)d_in[4];
  const float* wl_w = (const float*)d_in[5];
  const float* wl_b = (const float*)d_in[6];
  const float* lin_w = (const float*)d_in[7];
  const float* lin_b = (const float*)d_in[8];
  const int* edge_index = (const int*)d_in[9];
  const int* edge_type = (const int*)d_in[10];
  const int* h_set = (const int*)d_in[11];
  const int* r_set = (const int*)d_in[12];
  const int* t_index = (const int*)d_in[13];
  const int* hr_inverse = (const int*)d_in[14];
  float* out = (float*)d_out;

  const int* nin = edge_index;
  const int* nout = edge_index + kNE;

  // ---- workspace layout (regions sized to cover BOTH main & fallback) ----
  float* ws = (float*)d_ws;
  float* hidden = ws;                                   // 6*64*128
  float* attnAll = hidden + kNStep * kB * kHid;         // 6*6*64
  float* weightAll = attnAll + kNStep * kNStep * kB;    // 6*24*64
  float* colsumAll = weightAll + kNStep * kNRel2 * kB;  // 6*64
  float* inpRegion = colsumAll + kNStep * kB;           // kN1*64 f32 (covers inpT)
  __half* inpT = (__half*)inpRegion;                    // [64][kStride] fp16 view
  float* outsRegion = inpRegion + (long long)kN1 * kB;  // 6*64*kStride f32
  float* outsT = outsRegion;                            // main path view
  float* tail = outsRegion + (long long)kNStep * kB * kStride;
  int* counts = (int*)tail;                             // kN1
  int* offsets = counts + kN1;                          // kN1+1
  int* count2 = offsets + kN1 + 1;                      // kN1*8
  int* blockSum = count2 + kN1 * kNXcd;                 // 128
  unsigned* packed = (unsigned*)(blockSum + 128);       // kNE
  float* wt = (float*)(packed + kNE);                   // 256*512
  const size_t needed = (size_t)((char*)(wt + 256 * 512) - (char*)d_ws);

  if (ws_size >= needed) {
    transpose_w_kernel<<<512, 256, 0, stream>>>(w_ih, w_hh, wt);
    lstm_fast_kernel<<<kB, 512, 0, stream>>>(query_emb, wt, b_ih, b_hh, r_set, hidden);
    attn_weight_kernel<<<kB, 128, 0, stream>>>(hidden, wl_w, wl_b, attnAll, weightAll);

    zero_kernel<<<(kN1 * kNXcd + 255) / 256, 256, 0, stream>>>(count2, colsumAll);
    hist2_kernel<<<1024, 256, 0, stream>>>(nout, count2);
    scanA_kernel<<<kScanBlocks, 256, 0, stream>>>(count2, counts, blockSum);
    scanB_kernel<<<1, 128, 0, stream>>>(blockSum);
    scanC_kernel<<<kScanBlocks, 256, 0, stream>>>(counts, blockSum, count2, offsets);
    permute_kernel<<<1024, 256, 0, stream>>>(nin, nout, edge_type, count2, packed);

    for (int i = 0; i < kNStep; ++i) {
      float* outT_i = outsT + (long long)i * kB * kStride;
      inpT_kernel<<<kB * 10, 256, 0, stream>>>(attnAll, colsumAll, h_set, outsT,
                                               inpT, i);
      gather_cols_kernel<<<kB * kNChunk, 256, 0, stream>>>(
          inpT, weightAll + i * kNRel2 * kB, packed, offsets, outT_i,
          colsumAll + i * kB);
    }
    scoreT_kernel<<<(out_size + 255) / 256, 256, 0, stream>>>(
        outsT + 5LL * kB * kStride, colsumAll + 5 * kB, t_index, hr_inverse, lin_w,
        lin_b, out, out_size);
  } else {
    // ---- fallback: row-major atomic path ----
    float* inpF32 = inpRegion;
    float* outs = outsRegion;
    lstm_kernel<<<kB, 256, 0, stream>>>(query_emb, w_ih, w_hh, b_ih, b_hh, r_set,
                                        hidden);
    attn_weight_kernel<<<kB, 128, 0, stream>>>(hidden, wl_w, wl_b, attnAll, weightAll);
    float* colsum = colsumAll;
    for (int i = 0; i < kNStep; ++i) {
      float* out_i = outs + (long long)i * kN1 * kB;
      inp_zero_kernel<<<2048, 256, 0, stream>>>(attnAll, h_set, outs, inpF32, out_i,
                                                colsum, i);
      scatter_kernel<<<4096, 256, 0, stream>>>(inpF32, weightAll + i * kNRel2 * kB,
                                               nin, nout, edge_type, out_i, colsum);
      normalize_kernel<<<2048, 256, 0, stream>>>(out_i, colsum);
    }
    score_kernel_norm<<<(out_size + 255) / 256, 256, 0, stream>>>(
        outs + 5LL * kN1 * kB, t_index, hr_inverse, lin_w, lin_b, out, out_size);
  }
}